// Round 12
// baseline (196.044 us; speedup 1.0000x reference)
//
#include <hip/hip_runtime.h>
#include <hip/hip_bf16.h>

// ============================================================================
// fused stride-2 "transposed conv" + bias + channel-softmax + sigmoid
//
// PAD==OUT_PAD==1 => odd h or odd w outputs are the constant vector
// sigmoid(2*softmax(bias)). Even-even outputs are a dense 4x4 conv:
//   O[n,c,p,q] = sum_{ic,kh,kw} x[n,ic,p-kh,q-kw]*W[c,ic,kh,kw]
//
// R12: pipe-SUM reduction. R5-R11 invariant: per-CU work sums MFMA 57us +
// LDS 57us + L2-W 42us + VALU ~50us == measured 200us (zero overlap; every
// scheduling attack null). Halve the LDS term: wave = 2 Mtiles x 2 Ntiles
// (4 waves, 256 thr): per ks 4 W loads + 4 ds_reads -> 12 MFMAs (was 2+4->6
// per wave x8 waves: X read 8x per block, now 4x). LDS 57->29us.
// Numerics: bf16 hi/lo split (Whi*Xhi + Wlo*Xhi + Whi*Xlo), fp32 acc.
// ============================================================================

typedef __bf16 bf16x8 __attribute__((ext_vector_type(8)));
typedef float  f32x4  __attribute__((ext_vector_type(4)));
typedef float  f32x16 __attribute__((ext_vector_type(16)));
typedef unsigned short ushort_t;

#define TILE_P 8
#define TILE_Q 16
#define PATCH_R 11                    // TILE_P + 3
#define PATCH_C 19                    // TILE_Q + 3
#define XELEMS (PATCH_R*PATCH_C*64)   // 13376 bf16 per plane
#define XLO_BYTES (XELEMS*2)          // 26752
#define SMEM_BYTES (XELEMS*2*2)       // 53504 -> 3 blocks/CU (160.5KB/CU)
#define WSW_BYTES (16*4*4*2*64*16)    // 524288 bytes of W fragments
#define ODD_ROWS (32*128*64)          // 262144 odd output rows
#define ROWS_PER_BLOCK 183            // ceil(262144/1440)
#define NTROW_BYTES 4864              // +2 p-rows in X plane (2*19*64*2B)

// ---- prep: weight -> 32x32 fragment order, bf16 hi/lo ----------------------
// frag f = ((tap*4+icg)*4+Mt)*2+hl, 1KB each; lane l holds
// W[cout=Mt*32+(l&31)][ic=icg*16+(l>>5)*8+i]  (A-operand: row=l&31, k slice).
__global__ void prep_w_kernel(const float* __restrict__ w, ushort_t* __restrict__ wsW) {
    int slot = blockIdx.x * 256 + threadIdx.x;      // 32768 slots
    int lane = slot & 63;
    int hl   = (slot >> 6) & 1;
    int Mt   = (slot >> 7) & 3;
    int icg  = (slot >> 9) & 3;
    int tap  = slot >> 11;
    int kh = tap >> 2, kw = tap & 3;
    int cout = Mt * 32 + (lane & 31);
    int icb  = icg * 16 + (lane >> 5) * 8;
    bf16x8 v;
#pragma unroll
    for (int i = 0; i < 8; ++i) {
        float f = w[((cout * 64 + icb + i) * 4 + kh) * 4 + kw];
        __bf16 h = (__bf16)f;
        v[i] = hl ? (__bf16)(f - (float)h) : h;
    }
    *(bf16x8*)(wsW + (size_t)slot * 8) = v;   // slot*16 bytes
}

// ---- prep: const vector sigmoid(2*softmax(bias)) ---------------------------
__global__ void prep_const_kernel(const float* __restrict__ bias, float* __restrict__ wsc) {
    __shared__ float red[128];
    int t = threadIdx.x;
    red[t] = bias[t];
    __syncthreads();
    float m = -3.4e38f;
    for (int i = 0; i < 128; ++i) m = fmaxf(m, red[i]);
    float e = __expf(red[t] - m);
    __syncthreads();
    red[t] = e;
    __syncthreads();
    float s = 0.f;
    for (int i = 0; i < 128; ++i) s += red[i];
    float v = e / s;
    wsc[t] = 1.0f / (1.0f + __expf(-2.0f * v));
}

// ---- main ------------------------------------------------------------------
__launch_bounds__(256, 3)
__global__ void conv_main_kernel(const float* __restrict__ x,
                                 const float* __restrict__ bias,
                                 const ushort_t* __restrict__ wsW,
                                 const float* __restrict__ wsc,
                                 float* __restrict__ out) {
    extern __shared__ char smem[];
    ushort_t* xs = (ushort_t*)smem;

    const int tid = threadIdx.x;
    const int n   = blockIdx.z;
    const int p0  = blockIdx.y * TILE_P;
    const int q0  = blockIdx.x * TILE_Q;
    const int bid = (blockIdx.z * 9 + blockIdx.y) * 5 + blockIdx.x;

    const int lane = tid & 63;
    const int wv   = tid >> 6;       // 4 waves
    const int mtp  = wv & 1;         // Mtile pair base 2*mtp (64 couts)
    const int ntp  = wv >> 1;        // Ntile pair base 2*ntp (4 p-rows)
    const int l31  = lane & 31;
    const int lhi  = lane >> 5;
    const int qA   = l31 & 15;       // B col -> q offset
    const int dp   = l31 >> 4;       // B col -> p offset within Ntile

    // ---- stage X patch hi+lo, single pass ----------------------------------
    const float* xg = x + (size_t)n * 262144;
    for (int grp = tid; grp < PATCH_R * PATCH_C * 8; grp += 256) {
        int r   = grp / (PATCH_C * 8);
        int rem = grp - r * (PATCH_C * 8);
        int g   = rem / PATCH_C;
        int c   = rem - g * PATCH_C;
        int row = p0 + r - 3;
        int col = q0 + c - 3;
        bool ok = (row >= 0) & (row < 64) & (col >= 0) & (col < 64);
        const float* src = xg + (g * 8) * 4096 + row * 64 + col;
        bf16x8 hi, lo;
#pragma unroll
        for (int i = 0; i < 8; ++i) {
            float f = ok ? src[i * 4096] : 0.0f;
            __bf16 h = (__bf16)f;
            hi[i] = h;
            lo[i] = (__bf16)(f - (float)h);
        }
        int slot = ((r * PATCH_C + c) * 8 + (g ^ (c & 7))) * 8;     // elem idx
        *(bf16x8*)(xs + slot)          = hi;
        *(bf16x8*)(xs + XELEMS + slot) = lo;
    }
    __syncthreads();

    // ---- K loop: 64 Ksteps; 4 W loads + 4 ds_reads -> 12 MFMAs per wave ----
    f32x16 aA0 = (f32x16)(0.0f);   // Mt=2mtp,   Nt=2ntp
    f32x16 aA1 = (f32x16)(0.0f);   // Mt=2mtp,   Nt=2ntp+1
    f32x16 aB0 = (f32x16)(0.0f);   // Mt=2mtp+1, Nt=2ntp
    f32x16 aB1 = (f32x16)(0.0f);   // Mt=2mtp+1, Nt=2ntp+1

    const char* wb0 = (const char*)wsW + mtp * 4096 + lane * 16;
    const char* xsc = (const char*)smem;

#pragma unroll 4
    for (int ks = 0; ks < 64; ++ks) {
        int tap = ks >> 2, icg = ks & 3;
        int kh = tap >> 2, kw = tap & 3;
        int pc = qA + 3 - kw;
        int pr = ntp * 4 + dp + 3 - kh;
        int g8 = icg * 2 + lhi;
        int addr = (((pr * PATCH_C + pc) << 3) + (g8 ^ (pc & 7))) << 4;  // bytes

        const char* wp = wb0 + ks * 8192;
        bf16x8 w0h = *(const bf16x8*)(wp);
        bf16x8 w0l = *(const bf16x8*)(wp + 1024);
        bf16x8 w1h = *(const bf16x8*)(wp + 2048);
        bf16x8 w1l = *(const bf16x8*)(wp + 3072);

        bf16x8 xh0 = *(const bf16x8*)(xsc + addr);
        bf16x8 xl0 = *(const bf16x8*)(xsc + addr + XLO_BYTES);
        bf16x8 xh1 = *(const bf16x8*)(xsc + addr + NTROW_BYTES);
        bf16x8 xl1 = *(const bf16x8*)(xsc + addr + NTROW_BYTES + XLO_BYTES);

        aA0 = __builtin_amdgcn_mfma_f32_32x32x16_bf16(w0h, xh0, aA0, 0, 0, 0);
        aB0 = __builtin_amdgcn_mfma_f32_32x32x16_bf16(w1h, xh0, aB0, 0, 0, 0);
        aA1 = __builtin_amdgcn_mfma_f32_32x32x16_bf16(w0h, xh1, aA1, 0, 0, 0);
        aB1 = __builtin_amdgcn_mfma_f32_32x32x16_bf16(w1h, xh1, aB1, 0, 0, 0);
        aA0 = __builtin_amdgcn_mfma_f32_32x32x16_bf16(w0l, xh0, aA0, 0, 0, 0);
        aB0 = __builtin_amdgcn_mfma_f32_32x32x16_bf16(w1l, xh0, aB0, 0, 0, 0);
        aA1 = __builtin_amdgcn_mfma_f32_32x32x16_bf16(w0l, xh1, aA1, 0, 0, 0);
        aB1 = __builtin_amdgcn_mfma_f32_32x32x16_bf16(w1l, xh1, aB1, 0, 0, 0);
        aA0 = __builtin_amdgcn_mfma_f32_32x32x16_bf16(w0h, xl0, aA0, 0, 0, 0);
        aB0 = __builtin_amdgcn_mfma_f32_32x32x16_bf16(w1h, xl0, aB0, 0, 0, 0);
        aA1 = __builtin_amdgcn_mfma_f32_32x32x16_bf16(w0h, xl1, aA1, 0, 0, 0);
        aB1 = __builtin_amdgcn_mfma_f32_32x32x16_bf16(w1h, xl1, aB1, 0, 0, 0);
    }

    // ---- bias add: channel = mt*32 + (reg&3) + 8*(reg>>2) + 4*lhi ----------
    {
        f32x4 bvA[4], bvB[4];
#pragma unroll
        for (int j = 0; j < 4; ++j) {
            bvA[j] = *(const f32x4*)(bias + (2 * mtp + 0) * 32 + lhi * 4 + j * 8);
            bvB[j] = *(const f32x4*)(bias + (2 * mtp + 1) * 32 + lhi * 4 + j * 8);
        }
#pragma unroll
        for (int reg = 0; reg < 16; ++reg) {
            float a = bvA[reg >> 2][reg & 3];
            float b = bvB[reg >> 2][reg & 3];
            aA0[reg] += a; aA1[reg] += a;
            aB0[reg] += b; aB1[reg] += b;
        }
    }

    __syncthreads();                    // X planes dead -> overlay reduce bufs
    float* red1  = (float*)smem;        // [128 pos][2 mtp] max
    float* red2  = (float*)(smem + 1024);// [128 pos][2 mtp] sum
    float* cfill = (float*)(smem + 2048);// [128] const vector

    if (tid < 128) cfill[tid] = wsc[tid];

    // ---- per-position max: in-lane over 32 regs (2 Mt), shfl32, LDS x2 -----
    {
        float m0 = fmaxf(aA0[0], aB0[0]);
        float m1 = fmaxf(aA1[0], aB1[0]);
#pragma unroll
        for (int reg = 1; reg < 16; ++reg) {
            m0 = fmaxf(m0, fmaxf(aA0[reg], aB0[reg]));
            m1 = fmaxf(m1, fmaxf(aA1[reg], aB1[reg]));
        }
        m0 = fmaxf(m0, __shfl_xor(m0, 32));
        m1 = fmaxf(m1, __shfl_xor(m1, 32));
        if (lhi == 0) {
            red1[((2 * ntp + 0) * 32 + l31) * 2 + mtp] = m0;
            red1[((2 * ntp + 1) * 32 + l31) * 2 + mtp] = m1;
        }
    }
    __syncthreads();

    float gm[2];
#pragma unroll
    for (int j = 0; j < 2; ++j) {
        int pos = (2 * ntp + j) * 32 + l31;
        gm[j] = fmaxf(red1[pos * 2], red1[pos * 2 + 1]);
    }

    // ---- exp + per-position sum --------------------------------------------
    {
        float s0 = 0.f, s1 = 0.f;
#pragma unroll
        for (int reg = 0; reg < 16; ++reg) {
            float eA0 = __expf(aA0[reg] - gm[0]);
            float eB0 = __expf(aB0[reg] - gm[0]);
            float eA1 = __expf(aA1[reg] - gm[1]);
            float eB1 = __expf(aB1[reg] - gm[1]);
            aA0[reg] = eA0; aB0[reg] = eB0;
            aA1[reg] = eA1; aB1[reg] = eB1;
            s0 += eA0 + eB0;
            s1 += eA1 + eB1;
        }
        s0 += __shfl_xor(s0, 32);
        s1 += __shfl_xor(s1, 32);
        if (lhi == 0) {
            red2[((2 * ntp + 0) * 32 + l31) * 2 + mtp] = s0;
            red2[((2 * ntp + 1) * 32 + l31) * 2 + mtp] = s1;
        }
    }
    __syncthreads();

    float inv[2];
#pragma unroll
    for (int j = 0; j < 2; ++j) {
        int pos = (2 * ntp + j) * 32 + l31;
        inv[j] = 1.0f / (red2[pos * 2] + red2[pos * 2 + 1]);
    }

    // ---- normalize, sigmoid, store: 128B-contiguous per 16 lanes -----------
    {
        f32x4 cvA[4], cvB[4];
#pragma unroll
        for (int j = 0; j < 4; ++j) {
            cvA[j] = *(const f32x4*)(wsc + (2 * mtp + 0) * 32 + lhi * 4 + j * 8);
            cvB[j] = *(const f32x4*)(wsc + (2 * mtp + 1) * 32 + lhi * 4 + j * 8);
        }

        int q = q0 + qA;
#pragma unroll
        for (int j = 0; j < 2; ++j) {
            int p = p0 + (2 * ntp + j) * 2 + dp;
            if (p < 65 && q < 65) {
#pragma unroll
                for (int reg = 0; reg < 16; ++reg) {
                    int row = 4 * lhi + 8 * (reg >> 2) + (reg & 3);
                    float vA = (j == 0 ? aA0[reg] : aA1[reg]) * inv[j];
                    float vB = (j == 0 ? aB0[reg] : aB1[reg]) * inv[j];
                    float sgA = 1.0f / (1.0f + __expf(-2.0f * vA));
                    float sgB = 1.0f / (1.0f + __expf(-2.0f * vB));
                    int cA = (2 * mtp + 0) * 32 + row;
                    int cB = (2 * mtp + 1) * 32 + row;
                    size_t oA = ((size_t)(n * 128 + cA) * 129 + 2 * p) * 129 + 2 * q;
                    size_t oB = ((size_t)(n * 128 + cB) * 129 + 2 * p) * 129 + 2 * q;
                    if (q < 64) {
                        float2 prA = {sgA, cvA[reg >> 2][reg & 3]};
                        float2 prB = {sgB, cvB[reg >> 2][reg & 3]};
                        *(float2*)(out + oA) = prA;
                        *(float2*)(out + oB) = prB;
                    } else {
                        out[oA] = sgA;
                        out[oB] = sgB;
                    }
                }
            }
        }
    }

    // ---- merged odd-row const fill: 183 FULL 516B rows per block -----------
    {
        int rbase = bid * ROWS_PER_BLOCK;
        int t    = tid & 127;           // column 0..127
        int half = tid >> 7;            // 2 rows in flight
        for (int i = half; i < ROWS_PER_BLOCK; i += 2) {
            int r = rbase + i;
            if (r < ODD_ROWS) {
                int n2 = r >> 13;
                int c2 = (r >> 6) & 127;
                int oh = ((r & 63) << 1) + 1;
                float v = cfill[c2];
                size_t base = ((size_t)(n2 * 128 + c2) * 129 + oh) * 129;
                out[base + t] = v;
                if (t == 127) out[base + 128] = v;
            }
        }
    }
}

extern "C" void kernel_launch(void* const* d_in, const int* in_sizes, int n_in,
                              void* d_out, int out_size, void* d_ws, size_t ws_size,
                              hipStream_t stream) {
    const float* x    = (const float*)d_in[0];
    const float* w    = (const float*)d_in[1];
    const float* bias = (const float*)d_in[2];
    float* out = (float*)d_out;

    ushort_t* wsW = (ushort_t*)d_ws;                          // 512 KB
    float* wsc    = (float*)((char*)d_ws + WSW_BYTES);        // 512 B

    (void)hipFuncSetAttribute((const void*)conv_main_kernel,
                              hipFuncAttributeMaxDynamicSharedMemorySize, SMEM_BYTES);

    prep_w_kernel<<<128, 256, 0, stream>>>(w, wsW);
    prep_const_kernel<<<1, 128, 0, stream>>>(bias, wsc);

    dim3 grid(5, 9, 32);   // q-tiles, p-tiles, n
    conv_main_kernel<<<grid, 256, SMEM_BYTES, stream>>>(x, bias, wsW, wsc, out);
}

// Round 13
// 189.509 us; speedup vs baseline: 1.0345x; 1.0345x over previous
//
#include <hip/hip_runtime.h>
#include <hip/hip_bf16.h>

// ============================================================================
// fused stride-2 "transposed conv" + bias + channel-softmax + sigmoid
//
// PAD==OUT_PAD==1 => odd h or odd w outputs are the constant vector
// sigmoid(2*softmax(bias)). Even-even outputs are a dense 4x4 conv:
//   O[n,c,p,q] = sum_{ic,kh,kw} x[n,ic,p-kh,q-kw]*W[c,ic,kh,kw]
//
// R13: session-best structure (R6: TILE_P=4, 256thr, branch-free unroll-8
// K-loop, merged fill) + two low-risk grafts:
//  - T5 s_setprio(1) around the MFMA cluster (K-loop is barrier-free ->
//    wave-independent like attn, where setprio measured +4-7%)
//  - T1 bijective XCD swizzle (2720 blocks = 8 x 340): contiguous per-XCD
//    image slabs for x/W L2 locality.
// Model status: 641 TF == the 2-phase-class ceiling; 8-phase exit needs
// LDS (X 34-53KB + W dbuf 32-64KB) -> 1 block/CU, measured regression (R8).
// Numerics: bf16 hi/lo split (Whi*Xhi + Wlo*Xhi + Whi*Xlo), fp32 acc.
// ============================================================================

typedef __bf16 bf16x8 __attribute__((ext_vector_type(8)));
typedef float  f32x4  __attribute__((ext_vector_type(4)));
typedef float  f32x16 __attribute__((ext_vector_type(16)));
typedef unsigned short ushort_t;

#define TILE_P 4
#define TILE_Q 16
#define PATCH_R 7                     // TILE_P + 3
#define PATCH_C 19                    // TILE_Q + 3
#define XELEMS (PATCH_R*PATCH_C*64)   // 8512 bf16 per plane
#define XLO_BYTES (XELEMS*2)          // 17024
#define SMEM_BYTES (XELEMS*2*2)       // 34048 -> 4 blocks/CU
#define WSW_BYTES (16*4*4*2*64*16)    // 524288 bytes of W fragments
#define ODD_ROWS (32*128*64)          // 262144 odd output rows
#define ROWS_PER_BLOCK 97             // ceil(262144/2720)

// ---- prep: weight -> 32x32 fragment order, bf16 hi/lo ----------------------
// frag f = ((tap*4+icg)*4+Mt)*2+hl, 1KB each; lane l holds
// W[cout=Mt*32+(l&31)][ic=icg*16+(l>>5)*8+i]  (A-operand: row=l&31, k slice).
__global__ void prep_w_kernel(const float* __restrict__ w, ushort_t* __restrict__ wsW) {
    int slot = blockIdx.x * 256 + threadIdx.x;      // 32768 slots
    int lane = slot & 63;
    int hl   = (slot >> 6) & 1;
    int Mt   = (slot >> 7) & 3;
    int icg  = (slot >> 9) & 3;
    int tap  = slot >> 11;
    int kh = tap >> 2, kw = tap & 3;
    int cout = Mt * 32 + (lane & 31);
    int icb  = icg * 16 + (lane >> 5) * 8;
    bf16x8 v;
#pragma unroll
    for (int i = 0; i < 8; ++i) {
        float f = w[((cout * 64 + icb + i) * 4 + kh) * 4 + kw];
        __bf16 h = (__bf16)f;
        v[i] = hl ? (__bf16)(f - (float)h) : h;
    }
    *(bf16x8*)(wsW + (size_t)slot * 8) = v;   // slot*16 bytes
}

// ---- prep: const vector sigmoid(2*softmax(bias)) ---------------------------
__global__ void prep_const_kernel(const float* __restrict__ bias, float* __restrict__ wsc) {
    __shared__ float red[128];
    int t = threadIdx.x;
    red[t] = bias[t];
    __syncthreads();
    float m = -3.4e38f;
    for (int i = 0; i < 128; ++i) m = fmaxf(m, red[i]);
    float e = __expf(red[t] - m);
    __syncthreads();
    red[t] = e;
    __syncthreads();
    float s = 0.f;
    for (int i = 0; i < 128; ++i) s += red[i];
    float v = e / s;
    wsc[t] = 1.0f / (1.0f + __expf(-2.0f * v));
}

// ---- main ------------------------------------------------------------------
__launch_bounds__(256, 4)
__global__ void conv_main_kernel(const float* __restrict__ x,
                                 const float* __restrict__ bias,
                                 const ushort_t* __restrict__ wsW,
                                 const float* __restrict__ wsc,
                                 float* __restrict__ out) {
    extern __shared__ char smem[];
    ushort_t* xs = (ushort_t*)smem;

    const int tid = threadIdx.x;

    // ---- T1: bijective XCD swizzle (2720 = 8 * 340) ------------------------
    // dispatch index d goes to XCD d%8; remap so each XCD owns a contiguous
    // nid-slab (contiguous images/tiles -> x + W L2 locality per XCD).
    const int fid = (blockIdx.z * 17 + blockIdx.y) * 5 + blockIdx.x;
    const int nid = (fid & 7) * 340 + (fid >> 3);
    const int qt  = nid % 5;
    const int rem = nid / 5;
    const int pt  = rem % 17;
    const int n   = rem / 17;
    const int p0  = pt * TILE_P;
    const int q0  = qt * TILE_Q;

    const int lane = tid & 63;
    const int wv   = tid >> 6;       // wave id = Mtile (32 couts)
    const int l31  = lane & 31;
    const int lhi  = lane >> 5;
    const int qA   = l31 & 15;       // B col -> q offset
    const int dp   = l31 >> 4;       // B col -> p offset within Ntile

    // ---- stage X patch hi+lo, single pass ----------------------------------
    const float* xg = x + (size_t)n * 262144;
    for (int grp = tid; grp < PATCH_R * PATCH_C * 8; grp += 256) {
        int r   = grp / (PATCH_C * 8);
        int rm  = grp - r * (PATCH_C * 8);
        int g   = rm / PATCH_C;
        int c   = rm - g * PATCH_C;
        int row = p0 + r - 3;
        int col = q0 + c - 3;
        bool ok = (row >= 0) & (row < 64) & (col >= 0) & (col < 64);
        const float* src = xg + (g * 8) * 4096 + row * 64 + col;
        bf16x8 hi, lo;
#pragma unroll
        for (int i = 0; i < 8; ++i) {
            float f = ok ? src[i * 4096] : 0.0f;
            __bf16 h = (__bf16)f;
            hi[i] = h;
            lo[i] = (__bf16)(f - (float)h);
        }
        int slot = ((r * PATCH_C + c) * 8 + (g ^ (c & 7))) * 8;     // elem idx
        *(bf16x8*)(xs + slot)          = hi;
        *(bf16x8*)(xs + XELEMS + slot) = lo;
    }
    __syncthreads();

    // ---- K loop: 64 Ksteps, branch-free; T5 setprio around MFMA cluster ----
    f32x16 acc0 = (f32x16)(0.0f);
    f32x16 acc1 = (f32x16)(0.0f);

    const char* wbase = (const char*)wsW + wv * 2048 + lane * 16;
    const char* xsc   = (const char*)smem;

#pragma unroll 8
    for (int ks = 0; ks < 64; ++ks) {
        int tap = ks >> 2, icg = ks & 3;
        int kh = tap >> 2, kw = tap & 3;
        int pc = qA + 3 - kw;
        int pr = dp + 3 - kh;
        int g8 = icg * 2 + lhi;
        int addr = ((((pr * PATCH_C + pc) << 3) + (g8 ^ (pc & 7))) << 4);  // bytes

        const char* wp = wbase + ks * 8192;
        bf16x8 whi = *(const bf16x8*)(wp);
        bf16x8 wlo = *(const bf16x8*)(wp + 1024);
        bf16x8 xh0 = *(const bf16x8*)(xsc + addr);
        bf16x8 xl0 = *(const bf16x8*)(xsc + addr + XLO_BYTES);
        bf16x8 xh1 = *(const bf16x8*)(xsc + addr + 4864);             // +2 p-rows
        bf16x8 xl1 = *(const bf16x8*)(xsc + addr + 4864 + XLO_BYTES);

        __builtin_amdgcn_s_setprio(1);
        acc0 = __builtin_amdgcn_mfma_f32_32x32x16_bf16(whi, xh0, acc0, 0, 0, 0);
        acc1 = __builtin_amdgcn_mfma_f32_32x32x16_bf16(whi, xh1, acc1, 0, 0, 0);
        acc0 = __builtin_amdgcn_mfma_f32_32x32x16_bf16(wlo, xh0, acc0, 0, 0, 0);
        acc1 = __builtin_amdgcn_mfma_f32_32x32x16_bf16(wlo, xh1, acc1, 0, 0, 0);
        acc0 = __builtin_amdgcn_mfma_f32_32x32x16_bf16(whi, xl0, acc0, 0, 0, 0);
        acc1 = __builtin_amdgcn_mfma_f32_32x32x16_bf16(whi, xl1, acc1, 0, 0, 0);
        __builtin_amdgcn_s_setprio(0);
    }

    // ---- bias add: channel = wv*32 + (reg&3) + 8*(reg>>2) + 4*lhi ----------
    {
        f32x4 bv[4];
#pragma unroll
        for (int j = 0; j < 4; ++j)
            bv[j] = *(const f32x4*)(bias + wv * 32 + lhi * 4 + j * 8);
#pragma unroll
        for (int reg = 0; reg < 16; ++reg) {
            acc0[reg] += bv[reg >> 2][reg & 3];
            acc1[reg] += bv[reg >> 2][reg & 3];
        }
    }

    __syncthreads();                    // X planes dead -> overlay reduce bufs
    float* red1  = (float*)smem;        // [64 pos][4 waves] max
    float* red2  = (float*)(smem + 1024);// [64 pos][4 waves] sum
    float* cfill = (float*)(smem + 2048);// [128] const vector

    if (tid < 128) cfill[tid] = wsc[tid];

    // ---- per-position max: in-lane over 16 regs, shfl over lhi, LDS x4 -----
    {
        float m0 = acc0[0], m1 = acc1[0];
#pragma unroll
        for (int reg = 1; reg < 16; ++reg) {
            m0 = fmaxf(m0, acc0[reg]);
            m1 = fmaxf(m1, acc1[reg]);
        }
        m0 = fmaxf(m0, __shfl_xor(m0, 32));
        m1 = fmaxf(m1, __shfl_xor(m1, 32));
        if (lhi == 0) {
            red1[(0 * 32 + l31) * 4 + wv] = m0;
            red1[(1 * 32 + l31) * 4 + wv] = m1;
        }
    }
    __syncthreads();

    float gm[2];
#pragma unroll
    for (int nt = 0; nt < 2; ++nt) {
        f32x4 v = *(const f32x4*)&red1[(nt * 32 + l31) * 4];
        gm[nt] = fmaxf(fmaxf(v[0], v[1]), fmaxf(v[2], v[3]));
    }

    // ---- exp + per-position sum --------------------------------------------
    {
        float s0 = 0.f, s1 = 0.f;
#pragma unroll
        for (int reg = 0; reg < 16; ++reg) {
            float e0 = __expf(acc0[reg] - gm[0]);
            float e1 = __expf(acc1[reg] - gm[1]);
            acc0[reg] = e0; acc1[reg] = e1;
            s0 += e0; s1 += e1;
        }
        s0 += __shfl_xor(s0, 32);
        s1 += __shfl_xor(s1, 32);
        if (lhi == 0) {
            red2[(0 * 32 + l31) * 4 + wv] = s0;
            red2[(1 * 32 + l31) * 4 + wv] = s1;
        }
    }
    __syncthreads();

    float inv[2];
#pragma unroll
    for (int nt = 0; nt < 2; ++nt) {
        f32x4 v = *(const f32x4*)&red2[(nt * 32 + l31) * 4];
        inv[nt] = 1.0f / (v[0] + v[1] + v[2] + v[3]);
    }

    // ---- normalize, sigmoid, store: 128B-contiguous per 16 lanes -----------
    {
        f32x4 cv[4];
#pragma unroll
        for (int j = 0; j < 4; ++j)
            cv[j] = *(const f32x4*)(wsc + wv * 32 + lhi * 4 + j * 8);

        int q = q0 + qA;
#pragma unroll
        for (int nt = 0; nt < 2; ++nt) {
            int p = p0 + nt * 2 + dp;
            if (p < 65 && q < 65) {
#pragma unroll
                for (int reg = 0; reg < 16; ++reg) {
                    int c = wv * 32 + 4 * lhi + 8 * (reg >> 2) + (reg & 3);
                    float v  = (nt == 0 ? acc0[reg] : acc1[reg]) * inv[nt];
                    float sg = 1.0f / (1.0f + __expf(-2.0f * v));
                    size_t o = ((size_t)(n * 128 + c) * 129 + 2 * p) * 129 + 2 * q;
                    if (q < 64) {
                        float2 pr2 = {sg, cv[reg >> 2][reg & 3]};
                        *(float2*)(out + o) = pr2;
                    } else {
                        out[o] = sg;
                    }
                }
            }
        }
    }

    // ---- merged odd-row const fill: 97 FULL 516B rows per block ------------
    {
        int rbase = nid * ROWS_PER_BLOCK;
        int t    = tid & 127;           // column 0..127
        int half = tid >> 7;            // 2 rows in flight
        for (int i = half; i < ROWS_PER_BLOCK; i += 2) {
            int r = rbase + i;
            if (r < ODD_ROWS) {
                int n2 = r >> 13;
                int c2 = (r >> 6) & 127;
                int oh = ((r & 63) << 1) + 1;
                float v = cfill[c2];
                size_t base = ((size_t)(n2 * 128 + c2) * 129 + oh) * 129;
                out[base + t] = v;
                if (t == 127) out[base + 128] = v;
            }
        }
    }
}

extern "C" void kernel_launch(void* const* d_in, const int* in_sizes, int n_in,
                              void* d_out, int out_size, void* d_ws, size_t ws_size,
                              hipStream_t stream) {
    const float* x    = (const float*)d_in[0];
    const float* w    = (const float*)d_in[1];
    const float* bias = (const float*)d_in[2];
    float* out = (float*)d_out;

    ushort_t* wsW = (ushort_t*)d_ws;                          // 512 KB
    float* wsc    = (float*)((char*)d_ws + WSW_BYTES);        // 512 B

    (void)hipFuncSetAttribute((const void*)conv_main_kernel,
                              hipFuncAttributeMaxDynamicSharedMemorySize, SMEM_BYTES);

    prep_w_kernel<<<128, 256, 0, stream>>>(w, wsW);
    prep_const_kernel<<<1, 128, 0, stream>>>(bias, wsc);

    dim3 grid(5, 17, 32);   // q-tiles, p-tiles, n
    conv_main_kernel<<<grid, 256, SMEM_BYTES, stream>>>(x, bias, wsW, wsc, out);
}